// Round 3
// baseline (304.147 us; speedup 1.0000x reference)
//
#include <hip/hip_runtime.h>
#include <hip/hip_bf16.h>
#include <stdint.h>

#define Bb 8
#define Cc 128
#define Hh 96
#define Ww 160
#define HW (Hh*Ww)         // 15360
#define Kk 81

typedef __attribute__((ext_vector_type(8))) short short8;
typedef __attribute__((ext_vector_type(4))) float floatx4;
typedef __attribute__((ext_vector_type(4))) unsigned int uintx4;

__device__ __forceinline__ uint32_t bf16rne(float f) {
  uint32_t u = __float_as_uint(f);
  return (u + 0x7FFFu + ((u >> 16) & 1u)) >> 16;
}

// Block: 512 threads = 8 waves, pixel region 8h x 16w.
// MFMA 16x16x32 bf16: A = x2 q-row (16 wide), B = x1 pixels, K = 32 channels.
// R2 pipeline change: global->register prefetch of chunk ck+1 issued right
// after the post-store barrier, consumed (cvt+LDS write) next iteration.
// Hides ~900cy HBM latency behind MFMA + barrier + other waves' store phase.

__global__ __launch_bounds__(512, 4)
void corr_kernel(const float* __restrict__ x1, const float* __restrict__ x2,
                 float* __restrict__ out) {
  __shared__ __align__(16) ushort ldsX2[16*24*40];  // 30720 B
  __shared__ __align__(16) ushort ldsX1[8*16*40];   // 10240 B

  const int tid = threadIdx.x;
  const int w0 = blockIdx.x * 16;
  const int h0 = blockIdx.y * 8;
  const int b  = blockIdx.z;

  const int lane = tid & 63;
  const int wv   = tid >> 6;
  const int vy = wv & 3, vx = wv >> 2;
  const int n = lane & 15, quad = lane >> 4;
  const int s = n >> 3, pw = n & 7;

  // ---- precompute staging descriptors (chunk-invariant) ----
  const float* srcX2[3]; bool okX2[3]; int dstX2[3];
#pragma unroll
  for (int it = 0; it < 3; ++it) {
    int T   = it * 512 + tid;
    int w24 = T % 24;
    int t2  = T / 24;        // 0..63
    int rw  = t2 & 15;
    int cg  = t2 >> 4;       // 0..3
    int gh = h0 - 4 + rw;
    int gw = w0 - 4 + w24;
    bool ok = ((unsigned)gh < Hh) && ((unsigned)gw < Ww);
    int ghc = min(max(gh, 0), Hh - 1);
    int gwc = min(max(gw, 0), Ww - 1);
    srcX2[it] = x2 + ((size_t)(b*Cc + cg*8) * HW + ghc*Ww + gwc);
    okX2[it]  = ok;
    dstX2[it] = (rw*24 + w24)*40 + cg*8;
  }
  const float* srcX1; int dstX1;
  {
    int wl = tid & 15;
    int t2 = tid >> 4;       // 0..31
    int rl = t2 & 7;
    int cg = t2 >> 3;        // 0..3
    srcX1 = x1 + ((size_t)(b*Cc + cg*8) * HW + (h0 + rl)*Ww + (w0 + wl));
    dstX1 = (rl*16 + wl)*40 + cg*8;
  }

  // LDS read addresses (chunk-invariant)
  const ushort* bsrc = &ldsX1[((2*vy + s)*16 + 8*vx + pw)*40 + quad*8];
  const ushort* asrc0 = &ldsX2[(2*vy)*24*40 + (8*vx + n)*40 + quad*8];

  floatx4 acc[10];
#pragma unroll
  for (int t = 0; t < 10; ++t) acc[t] = (floatx4){0.f, 0.f, 0.f, 0.f};

  float r2[3][8], r1[8];

  // prefetch chunk 0
#pragma unroll
  for (int it = 0; it < 3; ++it)
#pragma unroll
    for (int k = 0; k < 8; ++k) r2[it][k] = srcX2[it][k*HW];
#pragma unroll
  for (int k = 0; k < 8; ++k) r1[k] = srcX1[k*HW];

#pragma unroll
  for (int ck = 0; ck < 4; ++ck) {
    if (ck) __syncthreads();   // prev chunk's MFMA reads done before overwrite

    // ---- convert prefetched regs -> LDS ----
#pragma unroll
    for (int it = 0; it < 3; ++it) {
      uint32_t p[4];
#pragma unroll
      for (int j = 0; j < 4; ++j) {
        float a = okX2[it] ? r2[it][2*j]   : 0.f;
        float bb= okX2[it] ? r2[it][2*j+1] : 0.f;
        p[j] = bf16rne(a) | (bf16rne(bb) << 16);
      }
      *(uintx4*)&ldsX2[dstX2[it]] = (uintx4){p[0], p[1], p[2], p[3]};
    }
    {
      uint32_t p[4];
#pragma unroll
      for (int j = 0; j < 4; ++j)
        p[j] = bf16rne(r1[2*j]) | (bf16rne(r1[2*j+1]) << 16);
      *(uintx4*)&ldsX1[dstX1] = (uintx4){p[0], p[1], p[2], p[3]};
    }

    __syncthreads();

    // ---- issue next chunk's global loads (consumed next iteration) ----
    if (ck < 3) {
      const int co = (ck + 1) * 32;
#pragma unroll
      for (int it = 0; it < 3; ++it)
#pragma unroll
        for (int k = 0; k < 8; ++k) r2[it][k] = srcX2[it][(co + k)*HW];
#pragma unroll
      for (int k = 0; k < 8; ++k) r1[k] = srcX1[(co + k)*HW];
    }

    // ---- MFMA on current LDS contents ----
    short8 bfrag = *(const short8*)bsrc;
#pragma unroll
    for (int t = 0; t < 10; ++t) {
      short8 afrag = *(const short8*)(asrc0 + t*24*40);
      acc[t] = __builtin_amdgcn_mfma_f32_16x16x32_bf16(afrag, bfrag, acc[t], 0, 0, 0);
    }
  }

  // ---- epilogue: scatter valid (di,dj) entries ----
  const float scale = 1.0f / 128.0f;
  const int ph  = h0 + 2*vy + s;
  const int pwg = w0 + 8*vx + pw;
#pragma unroll
  for (int t = 0; t < 10; ++t) {
    int di = t - 4 - s;
    if ((unsigned)(di + 4) > 8u) continue;
#pragma unroll
    for (int r = 0; r < 4; ++r) {
      int dj = quad*4 + r - 4 - pw;   // qw - pw
      if ((unsigned)(dj + 4) > 8u) continue;
      int kk = (di + 4) * 9 + (dj + 4);
      __builtin_nontemporal_store(acc[t][r] * scale,
          &out[((size_t)b*Kk + kk) * HW + ph*Ww + pwg]);
    }
  }
}

extern "C" void kernel_launch(void* const* d_in, const int* in_sizes, int n_in,
                              void* d_out, int out_size, void* d_ws, size_t ws_size,
                              hipStream_t stream) {
  const float* x1 = (const float*)d_in[0];
  const float* x2 = (const float*)d_in[1];
  float* out = (float*)d_out;
  dim3 grid(Ww/16, Hh/8, Bb);   // 10 x 12 x 8 = 960 blocks
  corr_kernel<<<grid, dim3(512, 1, 1), 0, stream>>>(x1, x2, out);
}

// Round 4
// 213.287 us; speedup vs baseline: 1.4260x; 1.4260x over previous
//
#include <hip/hip_runtime.h>
#include <hip/hip_bf16.h>
#include <stdint.h>

#define Bb 8
#define Cc 128
#define Hh 96
#define Ww 160
#define HW (Hh*Ww)         // 15360
#define Kk 81

typedef __attribute__((ext_vector_type(8))) short short8;
typedef __attribute__((ext_vector_type(4))) float floatx4;
typedef __attribute__((ext_vector_type(4))) unsigned int uintx4;

__device__ __forceinline__ uint32_t bf16rne(float f) {
  uint32_t u = __float_as_uint(f);
  return (u + 0x7FFFu + ((u >> 16) & 1u)) >> 16;
}

// Round-4: round-1 structure (load->cvt->LDS->MFMA per chunk, normal stores),
// tile widened 16w x 8h -> 32w x 8h. Staging rows are 40 contiguous floats
// (160 B segments vs 96 B) for DRAM page locality; x2 halo overfetch 3x->2.5x.
// 8 waves; wave = (vy = wv&3 -> h-rows 2vy,2vy+1; g = wv>>2 -> pw in [16g,16g+16)),
// each wave computes 2 MFMA n-sets (u=0,1). acc = 2x10x4 = 80 VGPRs.
// NO nontemporal stores (R3: nt tripled WRITE_SIZE via broken L2 write-merge).

__global__ __launch_bounds__(512, 4)
void corr_kernel(const float* __restrict__ x1, const float* __restrict__ x2,
                 float* __restrict__ out) {
  __shared__ __align__(16) ushort ldsX2[16*40*40];  // 51200 B
  __shared__ __align__(16) ushort ldsX1[8*32*40];   // 20480 B

  const int tid = threadIdx.x;
  const int w0 = blockIdx.x * 32;
  const int h0 = blockIdx.y * 8;
  const int b  = blockIdx.z;

  const int lane = tid & 63;
  const int wv   = tid >> 6;
  const int vy = wv & 3, g = wv >> 2;
  const int n = lane & 15, quad = lane >> 4;
  const int s = n >> 3, pwl = n & 7;

  floatx4 acc[2][10];
#pragma unroll
  for (int u = 0; u < 2; ++u)
#pragma unroll
    for (int t = 0; t < 10; ++t) acc[u][t] = (floatx4){0.f, 0.f, 0.f, 0.f};

  for (int ck = 0; ck < 4; ++ck) {
    const int c0 = ck * 32;
    if (ck) __syncthreads();   // protect LDS reuse from previous chunk

    // ---- stage x2: 16 rows x 40 w x 4 cgroups(8ch) = 2560 tasks ----
#pragma unroll
    for (int it = 0; it < 5; ++it) {
      int T   = it * 512 + tid;
      int w40 = T % 40;
      int t2  = T / 40;        // 0..63
      int rw  = t2 & 15;
      int cg  = t2 >> 4;       // 0..3
      int gh = h0 - 4 + rw;
      int gw = w0 - 4 + w40;
      bool ok = ((unsigned)gh < Hh) && ((unsigned)gw < Ww);
      const float* src = x2 + ((size_t)(b*Cc + c0 + cg*8) * HW + gh*Ww + gw);
      uint32_t p0, p1, p2, p3;
      {
        float a0 = ok ? src[0*HW] : 0.f;
        float a1 = ok ? src[1*HW] : 0.f;
        float a2 = ok ? src[2*HW] : 0.f;
        float a3 = ok ? src[3*HW] : 0.f;
        float a4 = ok ? src[4*HW] : 0.f;
        float a5 = ok ? src[5*HW] : 0.f;
        float a6 = ok ? src[6*HW] : 0.f;
        float a7 = ok ? src[7*HW] : 0.f;
        p0 = bf16rne(a0) | (bf16rne(a1) << 16);
        p1 = bf16rne(a2) | (bf16rne(a3) << 16);
        p2 = bf16rne(a4) | (bf16rne(a5) << 16);
        p3 = bf16rne(a6) | (bf16rne(a7) << 16);
      }
      *(uintx4*)&ldsX2[(rw*40 + w40)*40 + cg*8] = (uintx4){p0, p1, p2, p3};
    }

    // ---- stage x1: 8 rows x 32 w x 4 cgroups = 1024 tasks ----
#pragma unroll
    for (int it = 0; it < 2; ++it) {
      int T  = it * 512 + tid;
      int wl = T & 31;
      int t2 = T >> 5;         // 0..31
      int rl = t2 & 7;
      int cg = t2 >> 3;        // 0..3
      const float* src = x1 + ((size_t)(b*Cc + c0 + cg*8) * HW
                               + (h0 + rl)*Ww + (w0 + wl));
      uint32_t p0, p1, p2, p3;
      float a0 = src[0*HW], a1 = src[1*HW], a2 = src[2*HW], a3 = src[3*HW];
      float a4 = src[4*HW], a5 = src[5*HW], a6 = src[6*HW], a7 = src[7*HW];
      p0 = bf16rne(a0) | (bf16rne(a1) << 16);
      p1 = bf16rne(a2) | (bf16rne(a3) << 16);
      p2 = bf16rne(a4) | (bf16rne(a5) << 16);
      p3 = bf16rne(a6) | (bf16rne(a7) << 16);
      *(uintx4*)&ldsX1[(rl*32 + wl)*40 + cg*8] = (uintx4){p0, p1, p2, p3};
    }

    __syncthreads();

    // ---- compute: 2 n-sets per wave, 10 q-rows each ----
#pragma unroll
    for (int u = 0; u < 2; ++u) {
      short8 bfrag = *(const short8*)&ldsX1[((2*vy + s)*32 + 16*g + 8*u + pwl)*40 + quad*8];
#pragma unroll
      for (int t = 0; t < 10; ++t) {
        short8 afrag = *(const short8*)&ldsX2[((2*vy + t)*40 + 16*g + 8*u + n)*40 + quad*8];
        acc[u][t] = __builtin_amdgcn_mfma_f32_16x16x32_bf16(afrag, bfrag, acc[u][t], 0, 0, 0);
      }
    }
  }

  // ---- epilogue: scatter valid (di,dj) entries (normal stores) ----
  const float scale = 1.0f / 128.0f;
  const int ph = h0 + 2*vy + s;
#pragma unroll
  for (int u = 0; u < 2; ++u) {
    const int pwg = w0 + 16*g + 8*u + pwl;
#pragma unroll
    for (int t = 0; t < 10; ++t) {
      int di = t - 4 - s;
      if ((unsigned)(di + 4) > 8u) continue;
#pragma unroll
      for (int r = 0; r < 4; ++r) {
        int dj = quad*4 + r - 4 - pwl;   // qw - pw
        if ((unsigned)(dj + 4) > 8u) continue;
        int kk = (di + 4) * 9 + (dj + 4);
        out[((size_t)b*Kk + kk) * HW + ph*Ww + pwg] = acc[u][t][r] * scale;
      }
    }
  }
}

extern "C" void kernel_launch(void* const* d_in, const int* in_sizes, int n_in,
                              void* d_out, int out_size, void* d_ws, size_t ws_size,
                              hipStream_t stream) {
  const float* x1 = (const float*)d_in[0];
  const float* x2 = (const float*)d_in[1];
  float* out = (float*)d_out;
  dim3 grid(Ww/32, Hh/8, Bb);   // 5 x 12 x 8 = 480 blocks
  corr_kernel<<<grid, dim3(512, 1, 1), 0, stream>>>(x1, x2, out);
}

// Round 6
// 189.449 us; speedup vs baseline: 1.6054x; 1.1258x over previous
//
#include <hip/hip_runtime.h>
#include <stdint.h>

#define Bb 8
#define Cc 128
#define Hh 96
#define Ww 160
#define HW (Hh*Ww)         // 15360
#define Kk 81

typedef __attribute__((ext_vector_type(8))) short short8;
typedef __attribute__((ext_vector_type(4))) float floatx4;
typedef __attribute__((ext_vector_type(4))) unsigned int uintx4;

__device__ __forceinline__ uint32_t bf16rne(float f) {
  uint32_t u = __float_as_uint(f);
  return (u + 0x7FFFu + ((u >> 16) & 1u)) >> 16;
}

// R6: exact round-1 structure (96 us, known good) + XCD-aware block remap.
// Default grid (10,12,8): flat%8 puts w/h-adjacent tiles on DIFFERENT XCDs,
// so x2 halo re-reads (126 MB) miss the per-XCD L2. Remap: flat 1-D grid,
// b = flat%8 (batch pinned to one XCD), j = flat/8 row-major tile sweep ->
// neighboring tiles co-resident on the same XCD -> halo re-reads L2-hit.
// NO asm prefetch (R5: untracked asm loads -> compiler copies pending regs
// -> NaN). NO nontemporal stores (R3: 3x WRITE_SIZE).

__global__ __launch_bounds__(512, 4)
void corr_kernel(const float* __restrict__ x1, const float* __restrict__ x2,
                 float* __restrict__ out) {
  __shared__ __align__(16) ushort ldsX2[16*24*40];  // 30720 B
  __shared__ __align__(16) ushort ldsX1[8*16*40];   // 10240 B

  const int tid = threadIdx.x;
  const int flat = blockIdx.x;
  const int b  = flat & 7;         // XCD id == batch
  const int j  = flat >> 3;        // 0..119, row-major within batch
  const int by = j / 10;
  const int bx = j - by * 10;
  const int w0 = bx * 16;
  const int h0 = by * 8;

  const int lane = tid & 63;
  const int wv   = tid >> 6;
  const int vy = wv & 3, vx = wv >> 2;
  const int n = lane & 15, quad = lane >> 4;
  const int s = n >> 3, pw = n & 7;

  floatx4 acc[10];
#pragma unroll
  for (int t = 0; t < 10; ++t) acc[t] = (floatx4){0.f, 0.f, 0.f, 0.f};

  for (int ck = 0; ck < 4; ++ck) {
    const int c0 = ck * 32;
    if (ck) __syncthreads();   // protect LDS reuse from previous chunk

    // ---- stage x2: 16 rows x 24 w x 4 cgroups(8ch) = 1536 tasks ----
#pragma unroll
    for (int it = 0; it < 3; ++it) {
      int T   = it * 512 + tid;
      int w24 = T % 24;
      int t2  = T / 24;        // 0..63
      int rw  = t2 & 15;
      int cg  = t2 >> 4;       // 0..3
      int gh = h0 - 4 + rw;
      int gw = w0 - 4 + w24;
      bool ok = ((unsigned)gh < Hh) && ((unsigned)gw < Ww);
      const float* src = x2 + ((size_t)(b*Cc + c0 + cg*8) * HW + gh*Ww + gw);
      uint32_t p0, p1, p2, p3;
      {
        float a0 = ok ? src[0*HW] : 0.f;
        float a1 = ok ? src[1*HW] : 0.f;
        float a2 = ok ? src[2*HW] : 0.f;
        float a3 = ok ? src[3*HW] : 0.f;
        float a4 = ok ? src[4*HW] : 0.f;
        float a5 = ok ? src[5*HW] : 0.f;
        float a6 = ok ? src[6*HW] : 0.f;
        float a7 = ok ? src[7*HW] : 0.f;
        p0 = bf16rne(a0) | (bf16rne(a1) << 16);
        p1 = bf16rne(a2) | (bf16rne(a3) << 16);
        p2 = bf16rne(a4) | (bf16rne(a5) << 16);
        p3 = bf16rne(a6) | (bf16rne(a7) << 16);
      }
      *(uintx4*)&ldsX2[(rw*24 + w24)*40 + cg*8] = (uintx4){p0, p1, p2, p3};
    }

    // ---- stage x1: 8 rows x 16 w x 4 cgroups = 512 tasks (1/thread) ----
    {
      int T  = tid;
      int wl = T & 15;
      int t2 = T >> 4;         // 0..31
      int rl = t2 & 7;
      int cg = t2 >> 3;        // 0..3
      const float* src = x1 + ((size_t)(b*Cc + c0 + cg*8) * HW
                               + (h0 + rl)*Ww + (w0 + wl));
      uint32_t p0, p1, p2, p3;
      float a0 = src[0*HW], a1 = src[1*HW], a2 = src[2*HW], a3 = src[3*HW];
      float a4 = src[4*HW], a5 = src[5*HW], a6 = src[6*HW], a7 = src[7*HW];
      p0 = bf16rne(a0) | (bf16rne(a1) << 16);
      p1 = bf16rne(a2) | (bf16rne(a3) << 16);
      p2 = bf16rne(a4) | (bf16rne(a5) << 16);
      p3 = bf16rne(a6) | (bf16rne(a7) << 16);
      *(uintx4*)&ldsX1[(rl*16 + wl)*40 + cg*8] = (uintx4){p0, p1, p2, p3};
    }

    __syncthreads();

    // ---- compute: B frag once, 10 q-rows of A ----
    short8 bfrag = *(const short8*)&ldsX1[((2*vy + s)*16 + 8*vx + pw)*40 + quad*8];
#pragma unroll
    for (int t = 0; t < 10; ++t) {
      short8 afrag = *(const short8*)&ldsX2[((2*vy + t)*24 + 8*vx + n)*40 + quad*8];
      acc[t] = __builtin_amdgcn_mfma_f32_16x16x32_bf16(afrag, bfrag, acc[t], 0, 0, 0);
    }
  }

  // ---- epilogue: scatter valid (di,dj) entries ----
  const float scale = 1.0f / 128.0f;
  const int ph  = h0 + 2*vy + s;
  const int pwg = w0 + 8*vx + pw;
#pragma unroll
  for (int t = 0; t < 10; ++t) {
    int di = t - 4 - s;
    if ((unsigned)(di + 4) > 8u) continue;
#pragma unroll
    for (int r = 0; r < 4; ++r) {
      int dj = quad*4 + r - 4 - pw;   // qw - pw
      if ((unsigned)(dj + 4) > 8u) continue;
      int kk = (di + 4) * 9 + (dj + 4);
      out[((size_t)b*Kk + kk) * HW + ph*Ww + pwg] = acc[t][r] * scale;
    }
  }
}

extern "C" void kernel_launch(void* const* d_in, const int* in_sizes, int n_in,
                              void* d_out, int out_size, void* d_ws, size_t ws_size,
                              hipStream_t stream) {
  const float* x1 = (const float*)d_in[0];
  const float* x2 = (const float*)d_in[1];
  float* out = (float*)d_out;
  corr_kernel<<<dim3(960, 1, 1), dim3(512, 1, 1), 0, stream>>>(x1, x2, out);
}